// Round 14
// baseline (225.471 us; speedup 1.0000x reference)
//
#include <hip/hip_runtime.h>
#include <hip/hip_bf16.h>

typedef __bf16 bf16x8 __attribute__((ext_vector_type(8)));
typedef float f32x4 __attribute__((ext_vector_type(4)));
typedef float f32x8 __attribute__((ext_vector_type(8)));
typedef float f32x16 __attribute__((ext_vector_type(16)));
typedef unsigned short u16;
typedef unsigned int u32;

// B=4, S=2048, D=1024, H=16, Dh=64
#define SB 4
#define SS 2048
#define SD 1024
#define SH 16
#define SDH 64

__device__ __forceinline__ u16 f2bf(float f) {
  union { float f; u32 u; } x; x.f = f;
  u32 r = (x.u + 0x7FFFu + ((x.u >> 16) & 1u)) >> 16;
  return (u16)r;
}

__device__ __forceinline__ void gl_lds16(const void* g, void* l) {
  __builtin_amdgcn_global_load_lds(
      (__attribute__((address_space(1))) void*)g,
      (__attribute__((address_space(3))) void*)l, 16, 0, 0);
}

// ---------------- cast fp32 -> bf16 for q,k,v in ONE launch --------
__global__ void cast3_kernel(const float* __restrict__ q,
                             const float* __restrict__ k,
                             const float* __restrict__ v,
                             u32* __restrict__ oq, u32* __restrict__ ok,
                             u32* __restrict__ ov) {
  int sel = blockIdx.y;
  const float* in = (sel == 0) ? q : (sel == 1) ? k : v;
  u32* out = (sel == 0) ? oq : (sel == 1) ? ok : ov;
  int i = blockIdx.x * 256 + threadIdx.x;  // 4096 blocks x 256 thr, 8 elems
  const float4* inp = (const float4*)in;
  float4 a = inp[2 * i], b = inp[2 * i + 1];
  uint4 o;
  asm("v_cvt_pk_bf16_f32 %0, %1, %2" : "=v"(o.x) : "v"(a.x), "v"(a.y));
  asm("v_cvt_pk_bf16_f32 %0, %1, %2" : "=v"(o.y) : "v"(a.z), "v"(a.w));
  asm("v_cvt_pk_bf16_f32 %0, %1, %2" : "=v"(o.z) : "v"(b.x), "v"(b.y));
  asm("v_cvt_pk_bf16_f32 %0, %1, %2" : "=v"(o.w) : "v"(b.z), "v"(b.w));
  ((uint4*)out)[i] = o;
}

// ---------------- log2(w) precompute (8192 elems) ------------------
__global__ void log2w_kernel(const float* __restrict__ w,
                             float* __restrict__ lwg) {
  int i = blockIdx.x * 256 + threadIdx.x;
  lwg[i] = __builtin_amdgcn_logf(w[i]);  // v_log_f32 = log2
}

// ---------------- transpose + cast 4 weights: Wt[n][k] = W[k][n] ---
__global__ void transpose_cast_kernel(const float* __restrict__ W0,
                                      const float* __restrict__ W1,
                                      const float* __restrict__ W2,
                                      const float* __restrict__ W3,
                                      u16* __restrict__ T0,
                                      u16* __restrict__ T1,
                                      u16* __restrict__ T2,
                                      u16* __restrict__ T3) {
  __shared__ float t[32][33];
  int z = blockIdx.z;
  const float* W = (z == 0) ? W0 : (z == 1) ? W1 : (z == 2) ? W2 : W3;
  u16* Wt = (z == 0) ? T0 : (z == 1) ? T1 : (z == 2) ? T2 : T3;
  int bx = blockIdx.x, by = blockIdx.y;
  int tx = threadIdx.x, ty = threadIdx.y;  // 32 x 8
#pragma unroll
  for (int j = 0; j < 32; j += 8)
    t[ty + j][tx] = W[(size_t)(by * 32 + ty + j) * SD + bx * 32 + tx];
  __syncthreads();
#pragma unroll
  for (int j = 0; j < 32; j += 8)
    Wt[(size_t)(bx * 32 + ty + j) * SD + by * 32 + tx] = f2bf(t[tx][ty + j]);
}

// ---------------- merged Q/K/V projection GEMM (one launch) -------------
// grid 1536 = 3 modes x 512 blocks. 128x128 tile, BK=64, double-buffered;
// counted vmcnt(8) + raw barriers; bf16 gl_lds with pre-swizzled source,
// T2 XOR swizzle (byte ^= (row&7)<<4) on reads. Per-512-group XCD swizzle.
// mode 0: qb@WqT -> Qh[b][h][s][dh], scale log2e/8, bias[n]
// mode 1: kb@WkT -> Kf fragment-major, bias[n]
// mode 2: WvT@vb -> Vf fragment-major (M=1024,N=8192), bias[m]
__global__ __launch_bounds__(256, 2)
void gemm_qkv(const u16* __restrict__ qb, const u16* __restrict__ WqT,
              const float* __restrict__ bq, u16* __restrict__ Qh,
              const u16* __restrict__ kb, const u16* __restrict__ WkT,
              const float* __restrict__ bk, u16* __restrict__ Kf,
              const u16* __restrict__ WvT, const u16* __restrict__ vb,
              const float* __restrict__ bv, u16* __restrict__ Vf) {
  __shared__ u16 Asl[2][128 * 64];
  __shared__ u16 Bsl[2][128 * 64];
  int mode = blockIdx.x >> 9;          // 0,1,2
  int g = blockIdx.x & 511;
  int bid = (g & 7) * 64 + (g >> 3);   // XCD chunk swizzle within group
  const u16* A = (mode == 0) ? qb : (mode == 1) ? kb : WvT;
  const u16* Bt = (mode == 0) ? WqT : (mode == 1) ? WkT : vb;
  const float* bias = (mode == 0) ? bq : (mode == 1) ? bk : bv;
  u16* Out = (mode == 0) ? Qh : (mode == 1) ? Kf : Vf;
  const int K = 1024;
  const int ntile = (mode == 2) ? 64 : 8;
  int m0 = (bid / ntile) * 128, n0 = (bid % ntile) * 128;
  int tid = threadIdx.x;
  int lane = tid & 63, wv = tid >> 6;
  int wr = wv >> 1, wc = wv & 1;

  auto stage = [&](int buf, int k0) {
#pragma unroll
    for (int it = 0; it < 4; ++it) {
      int c = tid + it * 256;            // 1024 chunks of 16B per matrix
      int row = c >> 3, sl = c & 7;      // 8 x 16B per 128B row
      int ssl = sl ^ (row & 7);          // pre-swizzled source slot
      gl_lds16(A + (size_t)(m0 + row) * K + k0 + ssl * 8,
               (char*)&Asl[buf][0] + c * 16);
      gl_lds16(Bt + (size_t)(n0 + row) * K + k0 + ssl * 8,
               (char*)&Bsl[buf][0] + c * 16);
    }
  };

  f32x4 acc[4][4] = {};
  stage(0, 0);

  const int nk = 16;  // K/64
  for (int kt = 0; kt < nk; ++kt) {
    int buf = kt & 1;
    if (kt + 1 < nk) {
      stage(buf ^ 1, (kt + 1) << 6);
      asm volatile("s_waitcnt vmcnt(8) lgkmcnt(0)" ::: "memory");
    } else {
      asm volatile("s_waitcnt vmcnt(0) lgkmcnt(0)" ::: "memory");
    }
    __builtin_amdgcn_s_barrier();  // cur tile ready in LDS
#pragma unroll
    for (int kk = 0; kk < 2; ++kk) {
      bf16x8 af[4], bfr[4];
#pragma unroll
      for (int i = 0; i < 4; ++i) {
        int ar = wr * 64 + i * 16 + (lane & 15);
        int abyt = (ar * 128 + (kk * 32 + (lane >> 4) * 8) * 2) ^
                   ((ar & 7) << 4);
        af[i] = *(const bf16x8*)((const char*)&Asl[buf][0] + abyt);
        int br = wc * 64 + i * 16 + (lane & 15);
        int bbyt = (br * 128 + (kk * 32 + (lane >> 4) * 8) * 2) ^
                   ((br & 7) << 4);
        bfr[i] = *(const bf16x8*)((const char*)&Bsl[buf][0] + bbyt);
      }
#pragma unroll
      for (int i = 0; i < 4; ++i)
#pragma unroll
        for (int j = 0; j < 4; ++j)
          acc[i][j] = __builtin_amdgcn_mfma_f32_16x16x32_bf16(
              af[i], bfr[j], acc[i][j], 0, 0, 0);
    }
    __builtin_amdgcn_s_barrier();  // all waves done reading cur tile
  }

  int cg = lane >> 4, cc = lane & 15;
#pragma unroll
  for (int i = 0; i < 4; ++i) {
#pragma unroll
    for (int j = 0; j < 4; ++j) {
#pragma unroll
      for (int r = 0; r < 4; ++r) {
        int m = m0 + wr * 64 + i * 16 + cg * 4 + r;
        int n = n0 + wc * 64 + j * 16 + cc;
        float val = acc[i][j][r];
        if (mode == 0) {
          // fold (1/sqrt(Dh)) * log2(e) into Q for exp2-based softmax
          val = (val + bias[n]) * 0.18033688011112042f;
          int b = m >> 11, s2 = m & 2047, h = n >> 6, dh = n & 63;
          Out[((size_t)((b * SH + h) * SS + s2) << 6) + dh] = f2bf(val);
        } else if (mode == 1) {
          // Kf frag-major: frag(kb32=s>>5, st=dh>>4), lane=(s&31)|((dh&8)<<2)
          val += bias[n];
          int b = m >> 11, s2 = m & 2047, h = n >> 6, dh = n & 63;
          size_t off = ((size_t)(b * SH + h) << 17) +
                       ((size_t)(s2 >> 5) << 11) + ((size_t)(dh >> 4) << 9) +
                       ((size_t)((s2 & 31) | ((dh & 8) << 2)) << 3) +
                       (dh & 7);
          Out[off] = f2bf(val);
        } else {
          // Vf frag-major: frag(kb16=s>>4, dhh=dh>>5), lane=((s>>3)&1)*32+(dh&31)
          val += bias[m];  // m is the 1024-dim here
          int h = m >> 6, dh = m & 63, b = n >> 11, s2 = n & 2047;
          size_t off = ((size_t)(b * SH + h) << 17) +
                       ((size_t)(s2 >> 4) << 10) + ((size_t)(dh >> 5) << 9) +
                       ((size_t)(((s2 >> 3) & 1) * 32 + (dh & 31)) << 3) +
                       (s2 & 7);
          Out[off] = f2bf(val);
        }
      }
    }
  }
}

// ---------------- output projection GEMM (fp32 out + bias) --------------
__global__ __launch_bounds__(256, 2)
void gemm_out(const u16* __restrict__ A, const u16* __restrict__ Bt,
              const float* __restrict__ bias, float* __restrict__ Out,
              int M, int N, int K) {
  __shared__ u16 Asl[2][128 * 64];
  __shared__ u16 Bsl[2][128 * 64];
  const int ntile = N >> 7;
  int bid = blockIdx.x;
  bid = (bid & 7) * ((int)gridDim.x >> 3) + (bid >> 3);  // XCD chunk swizzle
  int m0 = (bid / ntile) * 128, n0 = (bid % ntile) * 128;
  int tid = threadIdx.x;
  int lane = tid & 63, wv = tid >> 6;
  int wr = wv >> 1, wc = wv & 1;

  auto stage = [&](int buf, int k0) {
#pragma unroll
    for (int it = 0; it < 4; ++it) {
      int c = tid + it * 256;
      int row = c >> 3, sl = c & 7;
      int ssl = sl ^ (row & 7);
      gl_lds16(A + (size_t)(m0 + row) * K + k0 + ssl * 8,
               (char*)&Asl[buf][0] + c * 16);
      gl_lds16(Bt + (size_t)(n0 + row) * K + k0 + ssl * 8,
               (char*)&Bsl[buf][0] + c * 16);
    }
  };

  f32x4 acc[4][4] = {};
  stage(0, 0);

  int nk = K >> 6;
  for (int kt = 0; kt < nk; ++kt) {
    int buf = kt & 1;
    if (kt + 1 < nk) {
      stage(buf ^ 1, (kt + 1) << 6);
      asm volatile("s_waitcnt vmcnt(8) lgkmcnt(0)" ::: "memory");
    } else {
      asm volatile("s_waitcnt vmcnt(0) lgkmcnt(0)" ::: "memory");
    }
    __builtin_amdgcn_s_barrier();
#pragma unroll
    for (int kk = 0; kk < 2; ++kk) {
      bf16x8 af[4], bfr[4];
#pragma unroll
      for (int i = 0; i < 4; ++i) {
        int ar = wr * 64 + i * 16 + (lane & 15);
        int abyt = (ar * 128 + (kk * 32 + (lane >> 4) * 8) * 2) ^
                   ((ar & 7) << 4);
        af[i] = *(const bf16x8*)((const char*)&Asl[buf][0] + abyt);
        int br = wc * 64 + i * 16 + (lane & 15);
        int bbyt = (br * 128 + (kk * 32 + (lane >> 4) * 8) * 2) ^
                   ((br & 7) << 4);
        bfr[i] = *(const bf16x8*)((const char*)&Bsl[buf][0] + bbyt);
      }
#pragma unroll
      for (int i = 0; i < 4; ++i)
#pragma unroll
        for (int j = 0; j < 4; ++j)
          acc[i][j] = __builtin_amdgcn_mfma_f32_16x16x32_bf16(
              af[i], bfr[j], acc[i][j], 0, 0, 0);
    }
    __builtin_amdgcn_s_barrier();
  }

  int cg = lane >> 4, cc = lane & 15;
#pragma unroll
  for (int i = 0; i < 4; ++i) {
#pragma unroll
    for (int j = 0; j < 4; ++j) {
#pragma unroll
      for (int r = 0; r < 4; ++r) {
        int m = m0 + wr * 64 + i * 16 + cg * 4 + r;
        int n = n0 + wc * 64 + j * 16 + cc;
        Out[(size_t)m * N + n] = acc[i][j][r] + bias[n];
      }
    }
  }
}

// ---------------- attention (R11 structure: 4 blocks/CU, counted vmcnt) -
// grid 1024 = 64 bh x 16 q-tiles of 128 rows. Block 256 thr = 4 waves,
// each wave 32 q-rows (u=1). Ring-2 K/V + lw row = 40KB -> 4 blocks/CU.
// K-wait vmcnt(2), V-wait vmcnt(4), stage(t+1) after the single per-tile
// raw barrier. Frag-major zero-conflict LDS reads; lwv as MFMA C-init.
__global__ __launch_bounds__(256, 4)
void attn_kernel(const u16* __restrict__ Qh, const u16* __restrict__ Kf,
                 const u16* __restrict__ Vf, const float* __restrict__ lwg,
                 u16* __restrict__ Ctx) {
  __shared__ u16 Kl[2][4096];   // 8KB per 64-key tile (16 x 1KB frags)
  __shared__ u16 Vl[2][4096];
  __shared__ float lwl[SS];     // log2(w) row (8KB)

  int bid = blockIdx.x;
  int swz = (bid & 7) * 128 + (bid >> 3);  // XCD chunk swizzle (1024 = 8*128)
  int bh = swz >> 4;                       // 0..63
  int qt = swz & 15;                       // 0..15
  int b = bh >> 4, hh = bh & 15;
  int q0 = qt * 128;
  int tid = threadIdx.x, lane = tid & 63, qw = tid >> 6;
  int ql = lane & 31, h = lane >> 5;
  const size_t basebh = (size_t)bh * (SS * SDH);
  const char* Ksrc = (const char*)(Kf + basebh);
  const char* Vsrc = (const char*)(Vf + basebh);

  // lw row -> LDS (retired before main loop; off the staging vmcnt path)
  {
    const float4* src = (const float4*)(lwg + b * SS);
    float4 r0 = src[tid];
    float4 r1 = src[tid + 256];
    ((float4*)lwl)[tid] = r0;
    ((float4*)lwl)[tid + 256] = r1;
  }

  // Q fragments: rows q0 + qw*32 + ql, dh = st*16 + h*8 + j
  bf16x8 qf[4];
  {
    const u16* qp = Qh + basebh + (size_t)(q0 + qw * 32 + ql) * SDH + h * 8;
#pragma unroll
    for (int st = 0; st < 4; ++st) qf[st] = *(const bf16x8*)(qp + st * 16);
  }

  auto stageK = [&](int s, int t) {
    const char* p = Ksrc + (size_t)t * 8192;
    gl_lds16(p + tid * 16, (char*)&Kl[s][0] + tid * 16);
    gl_lds16(p + 4096 + tid * 16, (char*)&Kl[s][0] + 4096 + tid * 16);
  };
  auto stageV = [&](int s, int t) {
    const char* p = Vsrc + (size_t)t * 8192;
    gl_lds16(p + tid * 16, (char*)&Vl[s][0] + tid * 16);
    gl_lds16(p + 4096 + tid * 16, (char*)&Vl[s][0] + 4096 + tid * 16);
  };

  f32x16 ctx0 = {}, ctx1 = {};
  float rs = 0.f;
  u32 pk[8][2];

  auto qk = [&](int t) {
    const char* Ks = (const char*)&Kl[t & 1][0];
    int kvb = t * 64;
#pragma unroll
    for (int kt = 0; kt < 2; ++kt) {
      bf16x8 kf[4];
#pragma unroll
      for (int st = 0; st < 4; ++st)
        kf[st] = *(const bf16x8*)(Ks + (kt * 4 + st) * 1024 + lane * 16);
      // C-init: lwv[e2*4+j] = log2w[kvb + kt*32 + e2*8 + h*4 + j]
      const float* lb = lwl + kvb + kt * 32 + h * 4;
      f32x4 l0 = *(const f32x4*)(lb);
      f32x4 l1 = *(const f32x4*)(lb + 8);
      f32x4 l2 = *(const f32x4*)(lb + 16);
      f32x4 l3 = *(const f32x4*)(lb + 24);
      f32x8 lo = __builtin_shufflevector(l0, l1, 0, 1, 2, 3, 4, 5, 6, 7);
      f32x8 hi = __builtin_shufflevector(l2, l3, 0, 1, 2, 3, 4, 5, 6, 7);
      f32x16 sc = __builtin_shufflevector(lo, hi, 0, 1, 2, 3, 4, 5, 6, 7, 8,
                                          9, 10, 11, 12, 13, 14, 15);
      __builtin_amdgcn_s_setprio(1);
#pragma unroll
      for (int st = 0; st < 4; ++st)
        sc = __builtin_amdgcn_mfma_f32_32x32x16_bf16(kf[st], qf[st], sc,
                                                     0, 0, 0);
      __builtin_amdgcn_s_setprio(0);
      // lane: P[q=ql][k = kvb + 32kt + (reg&3) + 8*(reg>>2) + 4h]
#pragma unroll
      for (int e2 = 0; e2 < 4; ++e2) {
        float v0 = __builtin_amdgcn_exp2f(sc[e2 * 4 + 0]);
        float v1 = __builtin_amdgcn_exp2f(sc[e2 * 4 + 1]);
        float v2 = __builtin_amdgcn_exp2f(sc[e2 * 4 + 2]);
        float v3 = __builtin_amdgcn_exp2f(sc[e2 * 4 + 3]);
        rs += (v0 + v1) + (v2 + v3);
        u32 p0, p1;
        asm("v_cvt_pk_bf16_f32 %0, %1, %2" : "=v"(p0) : "v"(v0), "v"(v1));
        asm("v_cvt_pk_bf16_f32 %0, %1, %2" : "=v"(p1) : "v"(v2), "v"(v3));
        pk[kt * 4 + e2][0] = p0;
        pk[kt * 4 + e2][1] = p1;
      }
    }
  };

  auto pv = [&](int t) {
    const char* Vs = (const char*)&Vl[t & 1][0];
#pragma unroll
    for (int ksl = 0; ksl < 4; ++ksl) {
      bf16x8 vf0 = *(const bf16x8*)(Vs + (ksl * 2 + 0) * 1024 + lane * 16);
      bf16x8 vf1 = *(const bf16x8*)(Vs + (ksl * 2 + 1) * 1024 + lane * 16);
      u32 d0 = pk[2 * ksl][0], d1 = pk[2 * ksl][1];
      u32 s0 = pk[2 * ksl + 1][0], s1 = pk[2 * ksl + 1][1];
      asm("v_permlane32_swap_b32 %0, %1" : "+v"(d0), "+v"(s0));
      asm("v_permlane32_swap_b32 %0, %1" : "+v"(d1), "+v"(s1));
      union { u32 uu[4]; bf16x8 v; } pa;
      pa.uu[0] = d0; pa.uu[1] = d1; pa.uu[2] = s0; pa.uu[3] = s1;
      __builtin_amdgcn_s_setprio(1);
      ctx0 = __builtin_amdgcn_mfma_f32_32x32x16_bf16(pa.v, vf0, ctx0, 0, 0, 0);
      ctx1 = __builtin_amdgcn_mfma_f32_32x32x16_bf16(pa.v, vf1, ctx1, 0, 0, 0);
      __builtin_amdgcn_s_setprio(0);
    }
  };

  // prologue staging: K0,V0 (4 counted loads)
  stageK(0, 0);
  stageV(0, 0);
  asm volatile("s_waitcnt lgkmcnt(0)" ::: "memory");
  __builtin_amdgcn_s_barrier();  // lwl visible; staging stays in flight

  for (int t = 0; t < 31; ++t) {
    asm volatile("s_waitcnt vmcnt(2)" ::: "memory");  // K(t) landed
    __builtin_amdgcn_s_barrier();  // all waves done with tile t-1 buffers
    stageK((t + 1) & 1, t + 1);
    stageV((t + 1) & 1, t + 1);
    qk(t);
    asm volatile("s_waitcnt vmcnt(4)" ::: "memory");  // V(t) landed
    pv(t);
  }
  // t = 31 (no staging)
  asm volatile("s_waitcnt vmcnt(2)" ::: "memory");
  __builtin_amdgcn_s_barrier();
  qk(31);
  asm volatile("s_waitcnt vmcnt(0)" ::: "memory");
  pv(31);

  // denominator + context write
  rs += __shfl_xor(rs, 32, 64);
  float rinv = 1.0f / (rs + 1e-12f);
#pragma unroll
  for (int reg = 0; reg < 16; ++reg) {
    int qrow = (reg & 3) + 8 * (reg >> 2) + 4 * h;
    float ri = __shfl(rinv, qrow, 64);
    int srow = q0 + qw * 32 + qrow;
    size_t base = ((size_t)(b * SS + srow) << 10) + hh * SDH;
    Ctx[base + ql] = f2bf(ctx0[reg] * ri);
    Ctx[base + 32 + ql] = f2bf(ctx1[reg] * ri);
  }
}

extern "C" void kernel_launch(void* const* d_in, const int* in_sizes, int n_in,
                              void* d_out, int out_size, void* d_ws,
                              size_t ws_size, hipStream_t stream) {
  const float* q = (const float*)d_in[0];
  const float* k = (const float*)d_in[1];
  const float* v = (const float*)d_in[2];
  const float* w = (const float*)d_in[3];
  const float* Wq = (const float*)d_in[4];
  const float* bq = (const float*)d_in[5];
  const float* Wk = (const float*)d_in[6];
  const float* bk = (const float*)d_in[7];
  const float* Wv = (const float*)d_in[8];
  const float* bv = (const float*)d_in[9];
  const float* Wo = (const float*)d_in[10];
  const float* bo = (const float*)d_in[11];
  float* out = (float*)d_out;

  char* ws = (char*)d_ws;
  const size_t SZ = (size_t)8192 * 1024 * 2;  // one bf16 [8192][1024] buffer
  u16* qb = (u16*)(ws);
  u16* kb = (u16*)(ws + SZ);
  u16* vb = (u16*)(ws + 2 * SZ);
  u16* WqT = (u16*)(ws + 3 * SZ);
  u16* WkT = WqT + 1024 * 1024;
  u16* WvT = WkT + 1024 * 1024;
  u16* WoT = WvT + 1024 * 1024;
  u16* Qh = (u16*)(ws + 3 * SZ + (size_t)4 * 1024 * 1024 * 2);
  u16* Kf = Qh + (size_t)8192 * 1024;
  u16* Vf = Kf + (size_t)8192 * 1024;
  float* lwg = (float*)(ws + 3 * SZ + (size_t)4 * 1024 * 1024 * 2 +
                        (size_t)3 * 8192 * 1024 * 2);
  u16* Ctx = qb;  // qb is dead after the Q projection

  // 1) casts (one launch) + tiny precomputes
  cast3_kernel<<<dim3(4096, 3), 256, 0, stream>>>(q, k, v, (u32*)qb,
                                                  (u32*)kb, (u32*)vb);
  log2w_kernel<<<32, 256, 0, stream>>>(w, lwg);
  dim3 tb(32, 8), tg(32, 32, 4);
  transpose_cast_kernel<<<tg, tb, 0, stream>>>(Wq, Wk, Wv, Wo,
                                               WqT, WkT, WvT, WoT);

  // 2) Q/K/V projections in ONE launch (1536 blocks)
  gemm_qkv<<<1536, 256, 0, stream>>>(qb, WqT, bq, Qh, kb, WkT, bk, Kf,
                                     WvT, vb, bv, Vf);

  // 3) attention (R11 structure)
  attn_kernel<<<1024, 256, 0, stream>>>(Qh, Kf, Vf, lwg, Ctx);

  // 4) output projection (fp32 out + bias)
  gemm_out<<<512, 256, 0, stream>>>(Ctx, WoT, bo, out, 8192, 1024, 1024);
}

// Round 15
// 209.729 us; speedup vs baseline: 1.0751x; 1.0751x over previous
//
#include <hip/hip_runtime.h>
#include <hip/hip_bf16.h>

typedef __bf16 bf16x8 __attribute__((ext_vector_type(8)));
typedef float f32x4 __attribute__((ext_vector_type(4)));
typedef float f32x8 __attribute__((ext_vector_type(8)));
typedef float f32x16 __attribute__((ext_vector_type(16)));
typedef unsigned short u16;
typedef unsigned int u32;

// B=4, S=2048, D=1024, H=16, Dh=64
#define SB 4
#define SS 2048
#define SD 1024
#define SH 16
#define SDH 64

__device__ __forceinline__ u16 f2bf(float f) {
  union { float f; u32 u; } x; x.f = f;
  u32 r = (x.u + 0x7FFFu + ((x.u >> 16) & 1u)) >> 16;
  return (u16)r;
}

__device__ __forceinline__ void gl_lds16(const void* g, void* l) {
  __builtin_amdgcn_global_load_lds(
      (__attribute__((address_space(1))) void*)g,
      (__attribute__((address_space(3))) void*)l, 16, 0, 0);
}

// ---------------- prep: cast q/k/v + weight transposes + log2w -----
// one launch: blocks [0,12288) cast, [12288,16384) transpose, rest log2w
__global__ void prep_kernel(const float* __restrict__ q,
                            const float* __restrict__ k,
                            const float* __restrict__ v,
                            u32* __restrict__ oq, u32* __restrict__ ok,
                            u32* __restrict__ ov,
                            const float* __restrict__ w,
                            float* __restrict__ lwg,
                            const float* __restrict__ W0,
                            const float* __restrict__ W1,
                            const float* __restrict__ W2,
                            const float* __restrict__ W3,
                            u16* __restrict__ T0, u16* __restrict__ T1,
                            u16* __restrict__ T2, u16* __restrict__ T3) {
  __shared__ float t[32][33];
  int bid = blockIdx.x, tid = threadIdx.x;
  if (bid < 12288) {
    int sel = bid >> 12;  // 4096 blocks per tensor
    int i = (bid & 4095) * 256 + tid;
    const float* in = (sel == 0) ? q : (sel == 1) ? k : v;
    u32* out = (sel == 0) ? oq : (sel == 1) ? ok : ov;
    const float4* inp = (const float4*)in;
    float4 a = inp[2 * i], b = inp[2 * i + 1];
    uint4 o;
    asm("v_cvt_pk_bf16_f32 %0, %1, %2" : "=v"(o.x) : "v"(a.x), "v"(a.y));
    asm("v_cvt_pk_bf16_f32 %0, %1, %2" : "=v"(o.y) : "v"(a.z), "v"(a.w));
    asm("v_cvt_pk_bf16_f32 %0, %1, %2" : "=v"(o.z) : "v"(b.x), "v"(b.y));
    asm("v_cvt_pk_bf16_f32 %0, %1, %2" : "=v"(o.w) : "v"(b.z), "v"(b.w));
    ((uint4*)out)[i] = o;
  } else if (bid < 16384) {
    int local = bid - 12288;  // 4096 = 4 * 32 * 32
    int z = local >> 10, by = (local >> 5) & 31, bx = local & 31;
    const float* W = (z == 0) ? W0 : (z == 1) ? W1 : (z == 2) ? W2 : W3;
    u16* Wt = (z == 0) ? T0 : (z == 1) ? T1 : (z == 2) ? T2 : T3;
    int tx = tid & 31, ty = tid >> 5;  // 32 x 8
#pragma unroll
    for (int j = 0; j < 32; j += 8)
      t[ty + j][tx] = W[(size_t)(by * 32 + ty + j) * SD + bx * 32 + tx];
    __syncthreads();
#pragma unroll
    for (int j = 0; j < 32; j += 8)
      Wt[(size_t)(bx * 32 + ty + j) * SD + by * 32 + tx] = f2bf(t[tx][ty + j]);
  } else {
    int i = (bid - 16384) * 256 + tid;
    lwg[i] = __builtin_amdgcn_logf(w[i]);  // v_log_f32 = log2
  }
}

// ---------------- GEMM: C[m][n] = sum_k A[m][k]*Bt[n][k] (+bias) ---
// 128x128 tile, BK=64, double-buffered; counted vmcnt(8), raw barriers.
// All operands bf16 via linear-dest gl_lds with pre-swizzled source,
// T2 XOR swizzle (byte ^= (row&7)<<4) on reads.
// MODE 0: -> Qh[b][h][s][dh] bf16 row-major, scale log2e/8, bias[n]
// MODE 1: -> Kf fragment-major (QK A-operand frags), bias[n]
// MODE 2: A=WvT, Bt=vb -> Vf fragment-major (PV B-operand), bias[m]
// MODE 3: -> fp32 [m][n] + bias[n]
template <int MODE>
__global__ __launch_bounds__(256, 2)
void gemm_bt(const u16* __restrict__ A, const u16* __restrict__ Bt,
             const float* __restrict__ bias, void* __restrict__ Out,
             int M, int N, int K) {
  __shared__ u16 Asl[2][128 * 64];
  __shared__ u16 Bsl[2][128 * 64];
  const int ntile = N >> 7;
  int bid = blockIdx.x;
  bid = (bid & 7) * ((int)gridDim.x >> 3) + (bid >> 3);  // XCD chunk swizzle
  int m0 = (bid / ntile) * 128, n0 = (bid % ntile) * 128;
  int tid = threadIdx.x;
  int lane = tid & 63, wv = tid >> 6;
  int wr = wv >> 1, wc = wv & 1;

  auto stage = [&](int buf, int k0) {
#pragma unroll
    for (int it = 0; it < 4; ++it) {
      int c = tid + it * 256;            // 1024 chunks of 16B per matrix
      int row = c >> 3, sl = c & 7;      // 8 x 16B per 128B row
      int ssl = sl ^ (row & 7);          // pre-swizzled source slot
      gl_lds16(A + (size_t)(m0 + row) * K + k0 + ssl * 8,
               (char*)&Asl[buf][0] + c * 16);
      gl_lds16(Bt + (size_t)(n0 + row) * K + k0 + ssl * 8,
               (char*)&Bsl[buf][0] + c * 16);
    }
  };

  f32x4 acc[4][4] = {};
  stage(0, 0);

  int nk = K >> 6;
  for (int kt = 0; kt < nk; ++kt) {
    int buf = kt & 1;
    if (kt + 1 < nk) {
      stage(buf ^ 1, (kt + 1) << 6);
      asm volatile("s_waitcnt vmcnt(8) lgkmcnt(0)" ::: "memory");
    } else {
      asm volatile("s_waitcnt vmcnt(0) lgkmcnt(0)" ::: "memory");
    }
    __builtin_amdgcn_s_barrier();  // cur tile ready in LDS
#pragma unroll
    for (int kk = 0; kk < 2; ++kk) {
      bf16x8 af[4], bfr[4];
#pragma unroll
      for (int i = 0; i < 4; ++i) {
        int ar = wr * 64 + i * 16 + (lane & 15);
        int abyt = (ar * 128 + (kk * 32 + (lane >> 4) * 8) * 2) ^
                   ((ar & 7) << 4);
        af[i] = *(const bf16x8*)((const char*)&Asl[buf][0] + abyt);
        int br = wc * 64 + i * 16 + (lane & 15);
        int bbyt = (br * 128 + (kk * 32 + (lane >> 4) * 8) * 2) ^
                   ((br & 7) << 4);
        bfr[i] = *(const bf16x8*)((const char*)&Bsl[buf][0] + bbyt);
      }
#pragma unroll
      for (int i = 0; i < 4; ++i)
#pragma unroll
        for (int j = 0; j < 4; ++j)
          acc[i][j] = __builtin_amdgcn_mfma_f32_16x16x32_bf16(
              af[i], bfr[j], acc[i][j], 0, 0, 0);
    }
    __builtin_amdgcn_s_barrier();  // all waves done reading cur tile
  }

  int cg = lane >> 4, cc = lane & 15;
#pragma unroll
  for (int i = 0; i < 4; ++i) {
#pragma unroll
    for (int j = 0; j < 4; ++j) {
#pragma unroll
      for (int r = 0; r < 4; ++r) {
        int m = m0 + wr * 64 + i * 16 + cg * 4 + r;
        int n = n0 + wc * 64 + j * 16 + cc;
        float val = acc[i][j][r];
        if (MODE == 0) {
          // fold (1/sqrt(Dh)) * log2(e) into Q for exp2-based softmax
          val = (val + bias[n]) * 0.18033688011112042f;
          int b = m >> 11, s2 = m & 2047, h = n >> 6, dh = n & 63;
          ((u16*)Out)[((size_t)((b * SH + h) * SS + s2) << 6) + dh] =
              f2bf(val);
        } else if (MODE == 1) {
          // Kf frag-major: frag(kb32=s>>5, st=dh>>4), lane=(s&31)|((dh&8)<<2)
          val += bias[n];
          int b = m >> 11, s2 = m & 2047, h = n >> 6, dh = n & 63;
          size_t off = ((size_t)(b * SH + h) << 17) +
                       ((size_t)(s2 >> 5) << 11) + ((size_t)(dh >> 4) << 9) +
                       ((size_t)((s2 & 31) | ((dh & 8) << 2)) << 3) +
                       (dh & 7);
          ((u16*)Out)[off] = f2bf(val);
        } else if (MODE == 2) {
          // Vf frag-major: frag(kb16=s>>4, dhh=dh>>5), lane=((s>>3)&1)*32+(dh&31)
          val += bias[m];  // m is the 1024-dim here
          int h = m >> 6, dh = m & 63, b = n >> 11, s2 = n & 2047;
          size_t off = ((size_t)(b * SH + h) << 17) +
                       ((size_t)(s2 >> 4) << 10) + ((size_t)(dh >> 5) << 9) +
                       ((size_t)(((s2 >> 3) & 1) * 32 + (dh & 31)) << 3) +
                       (s2 & 7);
          ((u16*)Out)[off] = f2bf(val);
        } else {
          val += bias[n];
          ((float*)Out)[(size_t)m * N + n] = val;
        }
      }
    }
  }
}

// ---------------- attention (R11 structure: 4 blocks/CU, counted vmcnt) -
// grid 1024 = 64 bh x 16 q-tiles of 128 rows. Block 256 thr = 4 waves,
// each wave 32 q-rows (u=1). Ring-2 K/V + lw row = 40KB -> 4 blocks/CU.
// K-wait vmcnt(2), V-wait vmcnt(4), stage(t+1) after the single per-tile
// raw barrier. Frag-major zero-conflict LDS reads; lwv as MFMA C-init.
__global__ __launch_bounds__(256, 4)
void attn_kernel(const u16* __restrict__ Qh, const u16* __restrict__ Kf,
                 const u16* __restrict__ Vf, const float* __restrict__ lwg,
                 u16* __restrict__ Ctx) {
  __shared__ u16 Kl[2][4096];   // 8KB per 64-key tile (16 x 1KB frags)
  __shared__ u16 Vl[2][4096];
  __shared__ float lwl[SS];     // log2(w) row (8KB)

  int bid = blockIdx.x;
  int swz = (bid & 7) * 128 + (bid >> 3);  // XCD chunk swizzle (1024 = 8*128)
  int bh = swz >> 4;                       // 0..63
  int qt = swz & 15;                       // 0..15
  int b = bh >> 4, hh = bh & 15;
  int q0 = qt * 128;
  int tid = threadIdx.x, lane = tid & 63, qw = tid >> 6;
  int ql = lane & 31, h = lane >> 5;
  const size_t basebh = (size_t)bh * (SS * SDH);
  const char* Ksrc = (const char*)(Kf + basebh);
  const char* Vsrc = (const char*)(Vf + basebh);

  // lw row -> LDS (retired before main loop; off the staging vmcnt path)
  {
    const float4* src = (const float4*)(lwg + b * SS);
    float4 r0 = src[tid];
    float4 r1 = src[tid + 256];
    ((float4*)lwl)[tid] = r0;
    ((float4*)lwl)[tid + 256] = r1;
  }

  // Q fragments: rows q0 + qw*32 + ql, dh = st*16 + h*8 + j
  bf16x8 qf[4];
  {
    const u16* qp = Qh + basebh + (size_t)(q0 + qw * 32 + ql) * SDH + h * 8;
#pragma unroll
    for (int st = 0; st < 4; ++st) qf[st] = *(const bf16x8*)(qp + st * 16);
  }

  auto stageK = [&](int s, int t) {
    const char* p = Ksrc + (size_t)t * 8192;
    gl_lds16(p + tid * 16, (char*)&Kl[s][0] + tid * 16);
    gl_lds16(p + 4096 + tid * 16, (char*)&Kl[s][0] + 4096 + tid * 16);
  };
  auto stageV = [&](int s, int t) {
    const char* p = Vsrc + (size_t)t * 8192;
    gl_lds16(p + tid * 16, (char*)&Vl[s][0] + tid * 16);
    gl_lds16(p + 4096 + tid * 16, (char*)&Vl[s][0] + 4096 + tid * 16);
  };

  f32x16 ctx0 = {}, ctx1 = {};
  float rs = 0.f;
  u32 pk[8][2];

  auto qk = [&](int t) {
    const char* Ks = (const char*)&Kl[t & 1][0];
    int kvb = t * 64;
#pragma unroll
    for (int kt = 0; kt < 2; ++kt) {
      bf16x8 kf[4];
#pragma unroll
      for (int st = 0; st < 4; ++st)
        kf[st] = *(const bf16x8*)(Ks + (kt * 4 + st) * 1024 + lane * 16);
      // C-init: lwv[e2*4+j] = log2w[kvb + kt*32 + e2*8 + h*4 + j]
      const float* lb = lwl + kvb + kt * 32 + h * 4;
      f32x4 l0 = *(const f32x4*)(lb);
      f32x4 l1 = *(const f32x4*)(lb + 8);
      f32x4 l2 = *(const f32x4*)(lb + 16);
      f32x4 l3 = *(const f32x4*)(lb + 24);
      f32x8 lo = __builtin_shufflevector(l0, l1, 0, 1, 2, 3, 4, 5, 6, 7);
      f32x8 hi = __builtin_shufflevector(l2, l3, 0, 1, 2, 3, 4, 5, 6, 7);
      f32x16 sc = __builtin_shufflevector(lo, hi, 0, 1, 2, 3, 4, 5, 6, 7, 8,
                                          9, 10, 11, 12, 13, 14, 15);
      __builtin_amdgcn_s_setprio(1);
#pragma unroll
      for (int st = 0; st < 4; ++st)
        sc = __builtin_amdgcn_mfma_f32_32x32x16_bf16(kf[st], qf[st], sc,
                                                     0, 0, 0);
      __builtin_amdgcn_s_setprio(0);
      // lane: P[q=ql][k = kvb + 32kt + (reg&3) + 8*(reg>>2) + 4h]
#pragma unroll
      for (int e2 = 0; e2 < 4; ++e2) {
        float v0 = __builtin_amdgcn_exp2f(sc[e2 * 4 + 0]);
        float v1 = __builtin_amdgcn_exp2f(sc[e2 * 4 + 1]);
        float v2 = __builtin_amdgcn_exp2f(sc[e2 * 4 + 2]);
        float v3 = __builtin_amdgcn_exp2f(sc[e2 * 4 + 3]);
        rs += (v0 + v1) + (v2 + v3);
        u32 p0, p1;
        asm("v_cvt_pk_bf16_f32 %0, %1, %2" : "=v"(p0) : "v"(v0), "v"(v1));
        asm("v_cvt_pk_bf16_f32 %0, %1, %2" : "=v"(p1) : "v"(v2), "v"(v3));
        pk[kt * 4 + e2][0] = p0;
        pk[kt * 4 + e2][1] = p1;
      }
    }
  };

  auto pv = [&](int t) {
    const char* Vs = (const char*)&Vl[t & 1][0];
#pragma unroll
    for (int ksl = 0; ksl < 4; ++ksl) {
      bf16x8 vf0 = *(const bf16x8*)(Vs + (ksl * 2 + 0) * 1024 + lane * 16);
      bf16x8 vf1 = *(const bf16x8*)(Vs + (ksl * 2 + 1) * 1024 + lane * 16);
      u32 d0 = pk[2 * ksl][0], d1 = pk[2 * ksl][1];
      u32 s0 = pk[2 * ksl + 1][0], s1 = pk[2 * ksl + 1][1];
      asm("v_permlane32_swap_b32 %0, %1" : "+v"(d0), "+v"(s0));
      asm("v_permlane32_swap_b32 %0, %1" : "+v"(d1), "+v"(s1));
      union { u32 uu[4]; bf16x8 v; } pa;
      pa.uu[0] = d0; pa.uu[1] = d1; pa.uu[2] = s0; pa.uu[3] = s1;
      __builtin_amdgcn_s_setprio(1);
      ctx0 = __builtin_amdgcn_mfma_f32_32x32x16_bf16(pa.v, vf0, ctx0, 0, 0, 0);
      ctx1 = __builtin_amdgcn_mfma_f32_32x32x16_bf16(pa.v, vf1, ctx1, 0, 0, 0);
      __builtin_amdgcn_s_setprio(0);
    }
  };

  // prologue staging: K0,V0 (4 counted loads)
  stageK(0, 0);
  stageV(0, 0);
  asm volatile("s_waitcnt lgkmcnt(0)" ::: "memory");
  __builtin_amdgcn_s_barrier();  // lwl visible; staging stays in flight

  for (int t = 0; t < 31; ++t) {
    asm volatile("s_waitcnt vmcnt(2)" ::: "memory");  // K(t) landed
    __builtin_amdgcn_s_barrier();  // all waves done with tile t-1 buffers
    stageK((t + 1) & 1, t + 1);
    stageV((t + 1) & 1, t + 1);
    qk(t);
    asm volatile("s_waitcnt vmcnt(4)" ::: "memory");  // V(t) landed
    pv(t);
  }
  // t = 31 (no staging)
  asm volatile("s_waitcnt vmcnt(2)" ::: "memory");
  __builtin_amdgcn_s_barrier();
  qk(31);
  asm volatile("s_waitcnt vmcnt(0)" ::: "memory");
  pv(31);

  // denominator + context write
  rs += __shfl_xor(rs, 32, 64);
  float rinv = 1.0f / (rs + 1e-12f);
#pragma unroll
  for (int reg = 0; reg < 16; ++reg) {
    int qrow = (reg & 3) + 8 * (reg >> 2) + 4 * h;
    float ri = __shfl(rinv, qrow, 64);
    int srow = q0 + qw * 32 + qrow;
    size_t base = ((size_t)(b * SS + srow) << 10) + hh * SDH;
    Ctx[base + ql] = f2bf(ctx0[reg] * ri);
    Ctx[base + 32 + ql] = f2bf(ctx1[reg] * ri);
  }
}

extern "C" void kernel_launch(void* const* d_in, const int* in_sizes, int n_in,
                              void* d_out, int out_size, void* d_ws,
                              size_t ws_size, hipStream_t stream) {
  const float* q = (const float*)d_in[0];
  const float* k = (const float*)d_in[1];
  const float* v = (const float*)d_in[2];
  const float* w = (const float*)d_in[3];
  const float* Wq = (const float*)d_in[4];
  const float* bq = (const float*)d_in[5];
  const float* Wk = (const float*)d_in[6];
  const float* bk = (const float*)d_in[7];
  const float* Wv = (const float*)d_in[8];
  const float* bv = (const float*)d_in[9];
  const float* Wo = (const float*)d_in[10];
  const float* bo = (const float*)d_in[11];
  float* out = (float*)d_out;

  char* ws = (char*)d_ws;
  const size_t SZ = (size_t)8192 * 1024 * 2;  // one bf16 [8192][1024] buffer
  u16* qb = (u16*)(ws);
  u16* kb = (u16*)(ws + SZ);
  u16* vb = (u16*)(ws + 2 * SZ);
  u16* WqT = (u16*)(ws + 3 * SZ);
  u16* WkT = WqT + 1024 * 1024;
  u16* WvT = WkT + 1024 * 1024;
  u16* WoT = WvT + 1024 * 1024;
  u16* Qh = (u16*)(ws + 3 * SZ + (size_t)4 * 1024 * 1024 * 2);
  u16* Kf = Qh + (size_t)8192 * 1024;
  u16* Vf = Kf + (size_t)8192 * 1024;
  float* lwg = (float*)(ws + 3 * SZ + (size_t)4 * 1024 * 1024 * 2 +
                        (size_t)3 * 8192 * 1024 * 2);
  u16* Ctx = qb;  // qb is dead after the Q projection

  // 1) prep: casts + weight transposes + log2w in ONE launch
  prep_kernel<<<16416, 256, 0, stream>>>(q, k, v, (u32*)qb, (u32*)kb,
                                         (u32*)vb, w, lwg, Wq, Wk, Wv, Wo,
                                         WqT, WkT, WvT, WoT);

  // 2) projections (separate launches — R14 showed merging thrashes L2)
  gemm_bt<0><<<512, 256, 0, stream>>>(qb, WqT, bq, Qh, 8192, 1024, 1024);
  gemm_bt<1><<<512, 256, 0, stream>>>(kb, WkT, bk, Kf, 8192, 1024, 1024);
  gemm_bt<2><<<512, 256, 0, stream>>>(WvT, vb, bv, Vf, 1024, 8192, 1024);

  // 3) attention (R11 structure: best measured, 86.0 µs)
  attn_kernel<<<1024, 256, 0, stream>>>(Qh, Kf, Vf, lwg, Ctx);

  // 4) output projection (fp32 out + bias)
  gemm_bt<3><<<512, 256, 0, stream>>>(Ctx, WoT, bo, out, 8192, 1024, 1024);
}